// Round 14
// baseline (516.618 us; speedup 1.0000x reference)
//
#include <hip/hip_runtime.h>
#include <stdint.h>
#include <stddef.h>

typedef __attribute__((ext_vector_type(8))) short bf16x8;
typedef __attribute__((ext_vector_type(4))) float f32x4;
typedef __attribute__((ext_vector_type(4))) unsigned int uint4v;

static __device__ __forceinline__ unsigned short f2bf(float f) {
  unsigned int u = __builtin_bit_cast(unsigned int, f);
  unsigned int r = (u + 0x7FFFu + ((u >> 16) & 1u)) >> 16;
  return (unsigned short)r;
}
static __device__ __forceinline__ float bf2f(unsigned short h) {
  unsigned int u = ((unsigned int)h) << 16;
  return __builtin_bit_cast(float, u);
}
static __device__ __forceinline__ unsigned int pk2(float a, float b) {
  return (unsigned int)f2bf(a) | ((unsigned int)f2bf(b) << 16);
}

static __device__ __forceinline__ void gld16(const void* g, void* l) {
  __builtin_amdgcn_global_load_lds(
      (const __attribute__((address_space(1))) void*)g,
      (__attribute__((address_space(3))) void*)l, 16, 0, 0);
}

__global__ void init_ctrs(int* c) {
  if (threadIdx.x < 4) c[threadIdx.x] = 0;
}

// ---------- fused: 4x weight transpose+cast (blocks 0..3839) + ln1 (blocks 3840..36607) ----------
__global__ __launch_bounds__(256) void fused_pre(
    const float* __restrict__ s0, unsigned short* __restrict__ d0,
    const float* __restrict__ s1, unsigned short* __restrict__ d1,
    const float* __restrict__ s2, unsigned short* __restrict__ d2,
    const float* __restrict__ s3, unsigned short* __restrict__ d3,
    const float* __restrict__ x, const float* __restrict__ gg,
    const float* __restrict__ bb, unsigned short* __restrict__ lnout) {
  __shared__ float tile[32][33];
  const int blk = blockIdx.x;
  if (blk < 3840) {
    const float* src; unsigned short* dst; int R, C, nbx, bi;
    if (blk < 1728)      { src = s0; dst = d0; R = 768;  C = 2304; nbx = 72; bi = blk; }
    else if (blk < 2304) { src = s1; dst = d1; R = 768;  C = 768;  nbx = 24; bi = blk - 1728; }
    else if (blk < 3072) { src = s2; dst = d2; R = 768;  C = 1024; nbx = 32; bi = blk - 2304; }
    else                 { src = s3; dst = d3; R = 1024; C = 768;  nbx = 24; bi = blk - 3072; }
    const int bx = bi % nbx, by = bi / nbx;
    const int c0 = bx * 32, r0 = by * 32;
    const int tx = threadIdx.x & 31, ty = threadIdx.x >> 5;
    #pragma unroll
    for (int i = 0; i < 32; i += 8)
      tile[ty + i][tx] = src[(size_t)(r0 + ty + i) * C + c0 + tx];
    __syncthreads();
    #pragma unroll
    for (int i = 0; i < 32; i += 8)
      dst[(size_t)(c0 + ty + i) * R + r0 + tx] = f2bf(tile[tx][ty + i]);
    return;
  }
  // ---- ln1: write shifted/window-partitioned rows ----
  float* sb = &tile[0][0];
  const int d = blk - 3840;
  int b = d >> 7, wid = (d >> 4) & 7, tok = d & 15;
  int oh = (((wid >> 2) << 2) + (tok >> 2) + 2) & 7;
  int ow = (((wid & 3) << 2) + (tok & 3) + 2) & 15;
  size_t srow = (size_t)(b << 7) + oh * 16 + ow;
  const int t = threadIdx.x;
  const bool ex = t < 128;
  float a0, a1, b0 = 0.f, b1 = 0.f;
  const float2* f2 = (const float2*)(x + srow * 768);
  float2 p = f2[t]; a0 = p.x; a1 = p.y;
  if (ex) { float2 q = f2[256 + t]; b0 = q.x; b1 = q.y; }
  float v = a0 + a1 + b0 + b1;
  #pragma unroll
  for (int o = 32; o > 0; o >>= 1) v += __shfl_down(v, o, 64);
  int lane = t & 63, w = t >> 6;
  __syncthreads();
  if (lane == 0) sb[w] = v;
  __syncthreads();
  float mean = (sb[0] + sb[1] + sb[2] + sb[3]) * (1.0f / 768.0f);
  float da0 = a0 - mean, da1 = a1 - mean, db0 = b0 - mean, db1 = b1 - mean;
  float vv = da0 * da0 + da1 * da1 + (ex ? db0 * db0 + db1 * db1 : 0.f);
  #pragma unroll
  for (int o = 32; o > 0; o >>= 1) vv += __shfl_down(vv, o, 64);
  __syncthreads();
  if (lane == 0) sb[w] = vv;
  __syncthreads();
  float var = (sb[0] + sb[1] + sb[2] + sb[3]) * (1.0f / 768.0f);
  float rstd = rsqrtf(var + 1e-5f);
  const float2* g2 = (const float2*)gg;
  const float2* be2 = (const float2*)bb;
  unsigned int* o32 = (unsigned int*)(lnout + (size_t)d * 768);
  float2 g = g2[t], be = be2[t];
  o32[t] = pk2(da0 * rstd * g.x + be.x, da1 * rstd * g.y + be.y);
  if (ex) {
    float2 gq = g2[256 + t], bq = be2[256 + t];
    o32[256 + t] = pk2(db0 * rstd * gq.x + bq.x, db1 * rstd * gq.y + bq.y);
  }
}

// ---------- block reduce ----------
static __device__ __forceinline__ float blksum256(float v, float* sb) {
  #pragma unroll
  for (int o = 32; o > 0; o >>= 1) v += __shfl_down(v, o, 64);
  int lane = threadIdx.x & 63, w = threadIdx.x >> 6;
  __syncthreads();
  if (lane == 0) sb[w] = v;
  __syncthreads();
  return sb[0] + sb[1] + sb[2] + sb[3];
}

// ---------- LayerNorm (ln2: bf16 input, identity rows) ----------
__global__ __launch_bounds__(256) void ln2_kernel(const unsigned short* __restrict__ xb,
                                                  const float* __restrict__ gg,
                                                  const float* __restrict__ bb,
                                                  unsigned short* __restrict__ out) {
  __shared__ float sb[4];
  const int d = blockIdx.x;
  const int t = threadIdx.x;
  const bool ex = t < 128;
  float a0, a1, b0 = 0.f, b1 = 0.f;
  const unsigned int* u = (const unsigned int*)(xb + (size_t)d * 768);
  unsigned int p = u[t];
  a0 = bf2f((unsigned short)p); a1 = bf2f((unsigned short)(p >> 16));
  if (ex) {
    unsigned int q = u[256 + t];
    b0 = bf2f((unsigned short)q); b1 = bf2f((unsigned short)(q >> 16));
  }
  float mean = blksum256(a0 + a1 + b0 + b1, sb) * (1.0f / 768.0f);
  float da0 = a0 - mean, da1 = a1 - mean, db0 = b0 - mean, db1 = b1 - mean;
  float var = blksum256(da0 * da0 + da1 * da1 + (ex ? db0 * db0 + db1 * db1 : 0.f), sb) *
              (1.0f / 768.0f);
  float rstd = rsqrtf(var + 1e-5f);
  const float2* g2 = (const float2*)gg;
  const float2* be2 = (const float2*)bb;
  unsigned int* o32 = (unsigned int*)(out + (size_t)d * 768);
  float2 g = g2[t], be = be2[t];
  o32[t] = pk2(da0 * rstd * g.x + be.x, da1 * rstd * g.y + be.y);
  if (ex) {
    float2 gq = g2[256 + t], bq = be2[256 + t];
    o32[256 + t] = pk2(db0 * rstd * gq.x + bq.x, db1 * rstd * gq.y + bq.y);
  }
}

// ---------- persistent 256x256 8-wave 8-phase GEMM with atomic work-stealing ----------
// Block claims tile bid, then steals subsequent tiles via atomicAdd, fetched one tile
// AHEAD so the next-tile prefetch (pAn/pBn staged during the last k-iteration) works
// unchanged. vmcnt(6)/barrier accounting identical to round 13 (proven).
// EPI 0: +bias -> bf16 (qkv)
// EPI 1: +bias, window-reverse+unshift scatter, +resid(x fp32) -> bf16 xr (proj)
// EPI 2: +bias, exact gelu -> bf16 (fc1)
// EPI 3: +bias, +residB(xr bf16) -> fp32 out (fc2)
template <int EPI>
__global__ __launch_bounds__(512, 2) void gemm256(
    const unsigned short* __restrict__ A, const unsigned short* __restrict__ BT,
    const float* __restrict__ bias, float* __restrict__ outF,
    unsigned short* __restrict__ outB, const float* __restrict__ resid,
    const unsigned short* __restrict__ residB,
    int M, int N, int K, int NT, int NTILES, int* __restrict__ ctr) {
  __shared__ __align__(16) unsigned short sA[2][256 * 64];
  __shared__ __align__(16) unsigned short sB[2][256 * 64];
  __shared__ int sh_vn;

  const int tid = threadIdx.x;
  const int lane = tid & 63, wv = tid >> 6;
  const int wr = wv >> 2, wc = wv & 3;
  const int fr = lane & 15, q4 = (lane >> 4) << 2;

  const size_t K2 = (size_t)K * 2;
  const int srow = tid >> 3;
  const int sg = tid & 7;
  const int sgs = ((sg ^ (srow & 7)) << 4);
  char* sdA = (char*)&sA[0][0] + (wv << 10);
  char* sdB = (char*)&sB[0][0] + (wv << 10);

  const int g0 = (((lane >> 4) ^ (fr & 7)) << 4);
  const int g1 = (((4 + (lane >> 4)) ^ (fr & 7)) << 4);
  const int arow = (wr << 7) + fr;
  const int brow = (wc << 6) + fr;

  // current tile = bid
  int v = blockIdx.x;
  int sw = (v & 7) * (NTILES >> 3) + (v >> 3);
  int m0 = (sw / NT) << 8, n0 = (sw - (sw / NT) * NT) << 8;
  const char* pA = (const char*)A + (size_t)(m0 + srow) * K2 + sgs;
  const char* pB = (const char*)BT + (size_t)(n0 + srow) * K2 + sgs;
  // steal next tile (one ahead)
  if (tid == 0) sh_vn = 256 + atomicAdd(ctr, 1);
  __syncthreads();
  int vn = sh_vn;
  bool more = vn < NTILES;
  int m0n = m0, n0n = n0;
  const char* pAn = pA; const char* pBn = pB;
  if (more) {
    int sw2 = (vn & 7) * (NTILES >> 3) + (vn >> 3);
    m0n = (sw2 / NT) << 8; n0n = (sw2 - (sw2 / NT) * NT) << 8;
    pAn = (const char*)A + (size_t)(m0n + srow) * K2 + sgs;
    pBn = (const char*)BT + (size_t)(n0n + srow) * K2 + sgs;
  }

  f32x4 acc[8][4];
  #pragma unroll
  for (int i = 0; i < 8; ++i)
    #pragma unroll
    for (int j = 0; j < 4; ++j) acc[i][j] = (f32x4){0.f, 0.f, 0.f, 0.f};

  bf16x8 af[4][2];
  bf16x8 bbv[2][2][2];
  const int KT = K >> 6;
  const int NI = KT >> 1;

#define BARR __builtin_amdgcn_s_barrier()
#define LGKM0 asm volatile("s_waitcnt lgkmcnt(0)" ::: "memory")
#define VM6 asm volatile("s_waitcnt vmcnt(6)" ::: "memory")
#define VM0 asm volatile("s_waitcnt vmcnt(0)" ::: "memory")

#define LDA(CB, mh)                                                          \
  {                                                                          \
    const char* ba = ((const char*)&sA[0][0]) + (CB)*32768;                  \
    _Pragma("unroll") for (int fm = 0; fm < 4; ++fm) {                       \
      const int r = arow + (mh)*64 + fm * 16;                                \
      af[fm][0] = *(const bf16x8*)(ba + r * 128 + g0);                       \
      af[fm][1] = *(const bf16x8*)(ba + r * 128 + g1);                       \
    }                                                                        \
  }
#define LDB(CB, nh)                                                          \
  {                                                                          \
    const char* ba = ((const char*)&sB[0][0]) + (CB)*32768;                  \
    _Pragma("unroll") for (int fn = 0; fn < 2; ++fn) {                       \
      const int r = brow + (nh)*32 + fn * 16;                                \
      bbv[nh][fn][0] = *(const bf16x8*)(ba + r * 128 + g0);                  \
      bbv[nh][fn][1] = *(const bf16x8*)(ba + r * 128 + g1);                  \
    }                                                                        \
  }
#define STGA_(P, CB, tt, j)                                                  \
  gld16((P) + (size_t)((j)*64) * K2 + ((size_t)(tt) << 7),                   \
        sdA + (CB)*32768 + (j)*8192);
#define STGB_(P, CB, tt, j)                                                  \
  gld16((P) + (size_t)((j)*64) * K2 + ((size_t)(tt) << 7),                   \
        sdB + (CB)*32768 + (j)*8192);
#define MMAQ(mh, nh)                                                         \
  _Pragma("unroll") for (int fm = 0; fm < 4; ++fm)                           \
      _Pragma("unroll") for (int fn = 0; fn < 2; ++fn) {                     \
    f32x4* ac = &acc[(mh)*4 + fm][(nh)*2 + fn];                              \
    *ac = __builtin_amdgcn_mfma_f32_16x16x32_bf16(af[fm][0], bbv[nh][fn][0], \
                                                  *ac, 0, 0, 0);             \
    *ac = __builtin_amdgcn_mfma_f32_16x16x32_bf16(af[fm][1], bbv[nh][fn][1], \
                                                  *ac, 0, 0, 0);             \
  }
#define OPEN  BARR; LGKM0; __builtin_amdgcn_s_setprio(1)
#define CLOSE __builtin_amdgcn_s_setprio(0)

  // prologue: first tile's k-tile 0 (8 chunks) + k-tile 1 (6 chunks; A1,A3 wrap to P0)
  #pragma unroll
  for (int j = 0; j < 4; ++j) { STGA_(pA, 0, 0, j); STGB_(pB, 0, 0, j); }
  STGA_(pA, 1, 1, 0); STGA_(pA, 1, 1, 2);
  STGB_(pB, 1, 1, 0); STGB_(pB, 1, 1, 1); STGB_(pB, 1, 1, 2); STGB_(pB, 1, 1, 3);
  VM6;
  BARR;

  for (;;) {
    for (int i = 0; i < NI; ++i) {
      const bool lastit = (i == NI - 1);
      const int s1 = 2 * i + 1;
      const bool gl = (!lastit) || more;
      const char* qA = lastit ? pAn : pA;
      const char* qB = lastit ? pBn : pB;
      const int t2 = lastit ? 0 : 2 * i + 2;
      const int t3 = lastit ? 1 : 2 * i + 3;
      // ---- K-tile 2i (buf0) ----
      LDB(0, 0) LDA(0, 0)
      STGA_(pA, 1, s1, 1); STGA_(pA, 1, s1, 3);
      OPEN; MMAQ(0, 0); CLOSE; BARR;
      LDB(0, 1)
      if (gl) { STGA_(qA, 0, t2, 0); STGA_(qA, 0, t2, 2); }
      OPEN; MMAQ(0, 1); CLOSE; BARR;
      LDA(0, 1)
      if (gl) { STGB_(qB, 0, t2, 0); STGB_(qB, 0, t2, 1); }
      OPEN; MMAQ(1, 1); CLOSE; BARR;
      if (gl) { STGB_(qB, 0, t2, 2); STGB_(qB, 0, t2, 3); }
      OPEN; MMAQ(1, 0); CLOSE;
      if (gl) { VM6; } else { VM0; }
      BARR;
      // ---- K-tile 2i+1 (buf1) ----
      LDB(1, 0) LDA(1, 0)
      if (gl) { STGA_(qA, 0, t2, 1); STGA_(qA, 0, t2, 3); }
      OPEN; MMAQ(0, 0); CLOSE; BARR;
      LDB(1, 1)
      if (gl) { STGA_(qA, 1, t3, 0); STGA_(qA, 1, t3, 2); }
      OPEN; MMAQ(0, 1); CLOSE; BARR;
      LDA(1, 1)
      if (gl) { STGB_(qB, 1, t3, 0); STGB_(qB, 1, t3, 1); }
      OPEN; MMAQ(1, 1); CLOSE; BARR;
      if (gl) { STGB_(qB, 1, t3, 2); STGB_(qB, 1, t3, 3); }
      OPEN; MMAQ(1, 0); CLOSE;
      if (gl) { VM6; }
      BARR;
    }

    // ---- epilogue for finished tile (m0, n0) ----
    #pragma unroll
    for (int ai = 0; ai < 8; ++ai) {
      #pragma unroll
      for (int bj = 0; bj < 4; ++bj) {
        const int col = n0 + (wc << 6) + bj * 16 + fr;
        const float bc = bias[col];
        #pragma unroll
        for (int i = 0; i < 4; ++i) {
          const int row = m0 + (wr << 7) + ai * 16 + q4 + i;
          float vvv = acc[ai][bj][i] + bc;
          if (EPI == 0) {
            outB[(size_t)row * N + col] = f2bf(vvv);
          } else if (EPI == 1) {
            int b = row >> 7, wid = (row >> 4) & 7, tok = row & 15;
            int oh = (((wid >> 2) << 2) + (tok >> 2) + 2) & 7;
            int ow = (((wid & 3) << 2) + (tok & 3) + 2) & 15;
            size_t di = ((size_t)(b << 7) + oh * 16 + ow) * 768 + col;
            outB[di] = f2bf(vvv + resid[di]);
          } else if (EPI == 2) {
            float g = 0.5f * vvv * (1.0f + erff(vvv * 0.70710678118f));
            outB[(size_t)row * N + col] = f2bf(g);
          } else {
            size_t di = (size_t)row * N + col;
            outF[di] = vvv + bf2f(residB[di]);
          }
          acc[ai][bj][i] = 0.f;
        }
      }
    }

    if (!more) break;
    v = vn;
    pA = pAn; pB = pBn; m0 = m0n; n0 = n0n;
    if (tid == 0) sh_vn = 256 + atomicAdd(ctr, 1);
    __syncthreads();
    vn = sh_vn;
    more = (vn < NTILES);
    if (more) {
      int sw2 = (vn & 7) * (NTILES >> 3) + (vn >> 3);
      m0n = (sw2 / NT) << 8; n0n = (sw2 - (sw2 / NT) * NT) << 8;
      pAn = (const char*)A + (size_t)(m0n + srow) * K2 + sgs;
      pBn = (const char*)BT + (size_t)(n0n + srow) * K2 + sgs;
    }
  }
#undef BARR
#undef LGKM0
#undef VM6
#undef VM0
#undef LDA
#undef LDB
#undef STGA_
#undef STGB_
#undef MMAQ
#undef OPEN
#undef CLOSE
}

// ---------- window attention: one wave per (window, head), coalesced O store ----------
__global__ __launch_bounds__(64) void attn_win(const unsigned short* __restrict__ qkv,
                                               const float* __restrict__ rel_table,
                                               unsigned short* __restrict__ o) {
  __shared__ __align__(16) unsigned short vt_s[64 * 32];
  __shared__ __align__(16) unsigned short p_s[16 * 32];
  __shared__ __align__(16) unsigned short o_s[16 * 72];
  const int nwg = gridDim.x;
  const int orig = blockIdx.x;
  const int bid = (orig & 7) * (nwg >> 3) + (orig >> 3);
  const int win = bid / 12;
  const int head = bid - win * 12;
  const int wid = win & 7;
  const int lane = threadIdx.x;
  const unsigned short* qb = qkv + (size_t)win * 16 * 2304 + head * 64;
  const int t = lane >> 2, d0 = (lane & 3) << 4;
  unsigned short vv[16];
  *(uint4v*)&vv[0] = *(const uint4v*)(qb + 1536 + (size_t)t * 2304 + d0);
  *(uint4v*)&vv[8] = *(const uint4v*)(qb + 1544 + (size_t)t * 2304 + d0);
  #pragma unroll
  for (int e = 0; e < 16; ++e) vt_s[(d0 + e) * 32 + t] = vv[e];
  #pragma unroll
  for (int e = 0; e < 16; ++e) vt_s[lane * 32 + 16 + e] = 0;
  if (lane < 16) {
    #pragma unroll
    for (int e = 0; e < 16; ++e) p_s[lane * 32 + 16 + e] = 0;
  }
  __syncthreads();

  const int fr = lane & 15, g8 = (lane >> 4) << 3;
  const unsigned short* qrow = qb + (size_t)fr * 2304;
  bf16x8 qa0 = *(const bf16x8*)(qrow + g8);
  bf16x8 qa1 = *(const bf16x8*)(qrow + 32 + g8);
  bf16x8 ka0 = *(const bf16x8*)(qrow + 768 + g8);
  bf16x8 ka1 = *(const bf16x8*)(qrow + 800 + g8);
  f32x4 s = (f32x4){0.f, 0.f, 0.f, 0.f};
  s = __builtin_amdgcn_mfma_f32_16x16x32_bf16(qa0, ka0, s, 0, 0, 0);
  s = __builtin_amdgcn_mfma_f32_16x16x32_bf16(qa1, ka1, s, 0, 0, 0);

  const int wh = wid >> 2, wwc = wid & 3;
  const int rj = fr >> 2, cj = fr & 3;
  const int rowm = wh * 4 + rj, colm = wwc * 4 + cj;
  const int rgm = (rowm < 4 ? 0 : (rowm < 6 ? 1 : 2)) * 3 +
                  (colm < 12 ? 0 : (colm < 14 ? 1 : 2));
  float p[4];
  #pragma unroll
  for (int i = 0; i < 4; ++i) {
    int n = ((lane >> 4) << 2) + i;
    int ri = n >> 2, ci = n & 3;
    int rown = wh * 4 + ri, coln = wwc * 4 + ci;
    int rgn = (rown < 4 ? 0 : (rown < 6 ? 1 : 2)) * 3 +
              (coln < 12 ? 0 : (coln < 14 ? 1 : 2));
    float bias = rel_table[(size_t)((ri - rj + 3) * 7 + (ci - cj + 3)) * 12 + head];
    p[i] = s[i] * 0.125f + bias + (rgn != rgm ? -100.0f : 0.0f);
  }
  float mx[4] = {p[0], p[1], p[2], p[3]};
  #pragma unroll
  for (int off = 8; off > 0; off >>= 1)
    #pragma unroll
    for (int i = 0; i < 4; ++i) mx[i] = fmaxf(mx[i], __shfl_xor(mx[i], off, 64));
  float sm[4];
  #pragma unroll
  for (int i = 0; i < 4; ++i) { p[i] = __expf(p[i] - mx[i]); sm[i] = p[i]; }
  #pragma unroll
  for (int off = 8; off > 0; off >>= 1)
    #pragma unroll
    for (int i = 0; i < 4; ++i) sm[i] += __shfl_xor(sm[i], off, 64);
  #pragma unroll
  for (int i = 0; i < 4; ++i)
    p_s[(((lane >> 4) << 2) + i) * 32 + fr] = f2bf(p[i] / sm[i]);
  __syncthreads();

  bf16x8 pa = *(const bf16x8*)&p_s[fr * 32 + g8];
  const f32x4 oz = (f32x4){0.f, 0.f, 0.f, 0.f};
  #pragma unroll
  for (int c = 0; c < 4; ++c) {
    bf16x8 vb = *(const bf16x8*)&vt_s[(c * 16 + fr) * 32 + g8];
    f32x4 oa = __builtin_amdgcn_mfma_f32_16x16x32_bf16(pa, vb, oz, 0, 0, 0);
    #pragma unroll
    for (int i = 0; i < 4; ++i) {
      int n = ((lane >> 4) << 2) + i;
      o_s[n * 72 + c * 16 + fr] = f2bf(oa[i]);
    }
  }
  __syncthreads();
  const int orow = lane >> 2, oq = lane & 3;
  const unsigned short* srcp = &o_s[orow * 72 + oq * 16];
  unsigned short* dstp = o + ((size_t)win * 16 + orow) * 768 + head * 64 + oq * 16;
  *(uint4v*)dstp = *(const uint4v*)srcp;
  *(uint4v*)(dstp + 8) = *(const uint4v*)(srcp + 8);
}

extern "C" void kernel_launch(void* const* d_in, const int* in_sizes, int n_in,
                              void* d_out, int out_size, void* d_ws, size_t ws_size,
                              hipStream_t stream) {
  const float* x      = (const float*)d_in[0];
  const float* ln1_g  = (const float*)d_in[1];
  const float* ln1_b  = (const float*)d_in[2];
  const float* qkv_w  = (const float*)d_in[3];
  const float* qkv_b  = (const float*)d_in[4];
  const float* proj_w = (const float*)d_in[5];
  const float* proj_b = (const float*)d_in[6];
  const float* rel_t  = (const float*)d_in[7];
  const float* ln2_g  = (const float*)d_in[8];
  const float* ln2_b  = (const float*)d_in[9];
  const float* fc1_w  = (const float*)d_in[10];
  const float* fc1_b  = (const float*)d_in[11];
  const float* fc2_w  = (const float*)d_in[12];
  const float* fc2_b  = (const float*)d_in[13];
  float* out = (float*)d_out;

  char* ws = (char*)d_ws;
  unsigned short* wsA = (unsigned short*)(ws);
  unsigned short* qkvb = (unsigned short*)(ws + 50331648);
  unsigned short* xr16 = (unsigned short*)(ws + 50331648);
  unsigned short* h1 = (unsigned short*)(ws + 201326592);
  unsigned short* qkv_wT = (unsigned short*)(ws + 268435456);  // [2304][768]
  unsigned short* proj_wT = (unsigned short*)(ws + 271974400); // [768][768]
  unsigned short* fc1_wT = (unsigned short*)(ws + 273154048);  // [1024][768]
  unsigned short* fc2_wT = (unsigned short*)(ws + 274726912);  // [768][1024]
  int* ctrs = (int*)(ws + 276299776);  // 4 steal counters (16 B pad after weights)

  init_ctrs<<<1, 64, 0, stream>>>(ctrs);
  fused_pre<<<36608, 256, 0, stream>>>(qkv_w, qkv_wT, proj_w, proj_wT,
                                       fc1_w, fc1_wT, fc2_w, fc2_wT,
                                       x, ln1_g, ln1_b, wsA);                    // weights + hw

  gemm256<0><<<256, 512, 0, stream>>>(wsA, qkv_wT, qkv_b, nullptr, qkvb,
                                      nullptr, nullptr,
                                      32768, 2304, 768, 9, 1152, ctrs + 0);      // qkv
  attn_win<<<24576, 64, 0, stream>>>(qkvb, rel_t, wsA);                          // o
  gemm256<1><<<256, 512, 0, stream>>>(wsA, proj_wT, proj_b, nullptr, xr16,
                                      x, nullptr,
                                      32768, 768, 768, 3, 384, ctrs + 1);        // xr16 = bf16(x + proj(o))
  ln2_kernel<<<32768, 256, 0, stream>>>(xr16, ln2_g, ln2_b, wsA);                // y
  gemm256<2><<<256, 512, 0, stream>>>(wsA, fc1_wT, fc1_b, nullptr, h1,
                                      nullptr, nullptr,
                                      32768, 1024, 768, 4, 512, ctrs + 2);       // h1 = gelu(...)
  gemm256<3><<<256, 512, 0, stream>>>(h1, fc2_wT, fc2_b, out, nullptr,
                                      nullptr, xr16,
                                      32768, 768, 1024, 3, 384, ctrs + 3);       // out = xr + fc2(h1)
}

// Round 15
// 495.553 us; speedup vs baseline: 1.0425x; 1.0425x over previous
//
#include <hip/hip_runtime.h>
#include <stdint.h>
#include <stddef.h>

typedef __attribute__((ext_vector_type(8))) short bf16x8;
typedef __attribute__((ext_vector_type(4))) float f32x4;
typedef __attribute__((ext_vector_type(4))) unsigned int uint4v;

static __device__ __forceinline__ unsigned short f2bf(float f) {
  unsigned int u = __builtin_bit_cast(unsigned int, f);
  unsigned int r = (u + 0x7FFFu + ((u >> 16) & 1u)) >> 16;
  return (unsigned short)r;
}
static __device__ __forceinline__ float bf2f(unsigned short h) {
  unsigned int u = ((unsigned int)h) << 16;
  return __builtin_bit_cast(float, u);
}
static __device__ __forceinline__ unsigned int pk2(float a, float b) {
  return (unsigned int)f2bf(a) | ((unsigned int)f2bf(b) << 16);
}

static __device__ __forceinline__ void gld16(const void* g, void* l) {
  __builtin_amdgcn_global_load_lds(
      (const __attribute__((address_space(1))) void*)g,
      (__attribute__((address_space(3))) void*)l, 16, 0, 0);
}

// ---------- fused: 4x weight transpose+cast (blocks 0..3839) + ln1 (blocks 3840..36607) ----------
__global__ __launch_bounds__(256) void fused_pre(
    const float* __restrict__ s0, unsigned short* __restrict__ d0,
    const float* __restrict__ s1, unsigned short* __restrict__ d1,
    const float* __restrict__ s2, unsigned short* __restrict__ d2,
    const float* __restrict__ s3, unsigned short* __restrict__ d3,
    const float* __restrict__ x, const float* __restrict__ gg,
    const float* __restrict__ bb, unsigned short* __restrict__ lnout) {
  __shared__ float tile[32][33];
  const int blk = blockIdx.x;
  if (blk < 3840) {
    const float* src; unsigned short* dst; int R, C, nbx, bi;
    if (blk < 1728)      { src = s0; dst = d0; R = 768;  C = 2304; nbx = 72; bi = blk; }
    else if (blk < 2304) { src = s1; dst = d1; R = 768;  C = 768;  nbx = 24; bi = blk - 1728; }
    else if (blk < 3072) { src = s2; dst = d2; R = 768;  C = 1024; nbx = 32; bi = blk - 2304; }
    else                 { src = s3; dst = d3; R = 1024; C = 768;  nbx = 24; bi = blk - 3072; }
    const int bx = bi % nbx, by = bi / nbx;
    const int c0 = bx * 32, r0 = by * 32;
    const int tx = threadIdx.x & 31, ty = threadIdx.x >> 5;
    #pragma unroll
    for (int i = 0; i < 32; i += 8)
      tile[ty + i][tx] = src[(size_t)(r0 + ty + i) * C + c0 + tx];
    __syncthreads();
    #pragma unroll
    for (int i = 0; i < 32; i += 8)
      dst[(size_t)(c0 + ty + i) * R + r0 + tx] = f2bf(tile[tx][ty + i]);
    return;
  }
  // ---- ln1: write shifted/window-partitioned rows ----
  float* sb = &tile[0][0];
  const int d = blk - 3840;
  int b = d >> 7, wid = (d >> 4) & 7, tok = d & 15;
  int oh = (((wid >> 2) << 2) + (tok >> 2) + 2) & 7;
  int ow = (((wid & 3) << 2) + (tok & 3) + 2) & 15;
  size_t srow = (size_t)(b << 7) + oh * 16 + ow;
  const int t = threadIdx.x;
  const bool ex = t < 128;
  float a0, a1, b0 = 0.f, b1 = 0.f;
  const float2* f2 = (const float2*)(x + srow * 768);
  float2 p = f2[t]; a0 = p.x; a1 = p.y;
  if (ex) { float2 q = f2[256 + t]; b0 = q.x; b1 = q.y; }
  float v = a0 + a1 + b0 + b1;
  #pragma unroll
  for (int o = 32; o > 0; o >>= 1) v += __shfl_down(v, o, 64);
  int lane = t & 63, w = t >> 6;
  __syncthreads();
  if (lane == 0) sb[w] = v;
  __syncthreads();
  float mean = (sb[0] + sb[1] + sb[2] + sb[3]) * (1.0f / 768.0f);
  float da0 = a0 - mean, da1 = a1 - mean, db0 = b0 - mean, db1 = b1 - mean;
  float vv = da0 * da0 + da1 * da1 + (ex ? db0 * db0 + db1 * db1 : 0.f);
  #pragma unroll
  for (int o = 32; o > 0; o >>= 1) vv += __shfl_down(vv, o, 64);
  __syncthreads();
  if (lane == 0) sb[w] = vv;
  __syncthreads();
  float var = (sb[0] + sb[1] + sb[2] + sb[3]) * (1.0f / 768.0f);
  float rstd = rsqrtf(var + 1e-5f);
  const float2* g2 = (const float2*)gg;
  const float2* be2 = (const float2*)bb;
  unsigned int* o32 = (unsigned int*)(lnout + (size_t)d * 768);
  float2 g = g2[t], be = be2[t];
  o32[t] = pk2(da0 * rstd * g.x + be.x, da1 * rstd * g.y + be.y);
  if (ex) {
    float2 gq = g2[256 + t], bq = be2[256 + t];
    o32[256 + t] = pk2(db0 * rstd * gq.x + bq.x, db1 * rstd * gq.y + bq.y);
  }
}

// ---------- block reduce ----------
static __device__ __forceinline__ float blksum256(float v, float* sb) {
  #pragma unroll
  for (int o = 32; o > 0; o >>= 1) v += __shfl_down(v, o, 64);
  int lane = threadIdx.x & 63, w = threadIdx.x >> 6;
  __syncthreads();
  if (lane == 0) sb[w] = v;
  __syncthreads();
  return sb[0] + sb[1] + sb[2] + sb[3];
}

// ---------- LayerNorm (ln2: bf16 input, identity rows) ----------
__global__ __launch_bounds__(256) void ln2_kernel(const unsigned short* __restrict__ xb,
                                                  const float* __restrict__ gg,
                                                  const float* __restrict__ bb,
                                                  unsigned short* __restrict__ out) {
  __shared__ float sb[4];
  const int d = blockIdx.x;
  const int t = threadIdx.x;
  const bool ex = t < 128;
  float a0, a1, b0 = 0.f, b1 = 0.f;
  const unsigned int* u = (const unsigned int*)(xb + (size_t)d * 768);
  unsigned int p = u[t];
  a0 = bf2f((unsigned short)p); a1 = bf2f((unsigned short)(p >> 16));
  if (ex) {
    unsigned int q = u[256 + t];
    b0 = bf2f((unsigned short)q); b1 = bf2f((unsigned short)(q >> 16));
  }
  float mean = blksum256(a0 + a1 + b0 + b1, sb) * (1.0f / 768.0f);
  float da0 = a0 - mean, da1 = a1 - mean, db0 = b0 - mean, db1 = b1 - mean;
  float var = blksum256(da0 * da0 + da1 * da1 + (ex ? db0 * db0 + db1 * db1 : 0.f), sb) *
              (1.0f / 768.0f);
  float rstd = rsqrtf(var + 1e-5f);
  const float2* g2 = (const float2*)gg;
  const float2* be2 = (const float2*)bb;
  unsigned int* o32 = (unsigned int*)(out + (size_t)d * 768);
  float2 g = g2[t], be = be2[t];
  o32[t] = pk2(da0 * rstd * g.x + be.x, da1 * rstd * g.y + be.y);
  if (ex) {
    float2 gq = g2[256 + t], bq = be2[256 + t];
    o32[256 + t] = pk2(db0 * rstd * gq.x + bq.x, db1 * rstd * gq.y + bq.y);
  }
}

// ---------- persistent 256x256 8-wave 8-phase GEMM, STATIC tile schedule ----------
// Block b processes tiles b, b+256, b+512, ... (bijective XCD swizzle on tile index
// keeps a block's tiles in one XCD's chunk -> L2 panel locality; round-14's dynamic
// stealing broke this, FETCH 100->158MB). Staging pipeline never drains between
// tiles: boundary iteration's s2/s3 chunks target the NEXT tile's k-tiles 0/1.
// EPI 0: +bias -> bf16 (qkv)
// EPI 1: +bias, window-reverse+unshift scatter, +resid(x fp32) -> bf16 xr (proj)
// EPI 2: +bias, exact gelu -> bf16 (fc1)
// EPI 3: +bias, +residB(xr bf16) -> fp32 out (fc2)
template <int EPI>
__global__ __launch_bounds__(512, 2) void gemm256(
    const unsigned short* __restrict__ A, const unsigned short* __restrict__ BT,
    const float* __restrict__ bias, float* __restrict__ outF,
    unsigned short* __restrict__ outB, const float* __restrict__ resid,
    const unsigned short* __restrict__ residB,
    int M, int N, int K, int NT, int NTILES) {
  __shared__ __align__(16) unsigned short sA[2][256 * 64];
  __shared__ __align__(16) unsigned short sB[2][256 * 64];

  const int tid = threadIdx.x;
  const int lane = tid & 63, wv = tid >> 6;
  const int wr = wv >> 2, wc = wv & 3;
  const int fr = lane & 15, q4 = (lane >> 4) << 2;

  const size_t K2 = (size_t)K * 2;
  const int srow = tid >> 3;
  const int sg = tid & 7;
  const int sgs = ((sg ^ (srow & 7)) << 4);
  char* sdA = (char*)&sA[0][0] + (wv << 10);
  char* sdB = (char*)&sB[0][0] + (wv << 10);

  const int g0 = (((lane >> 4) ^ (fr & 7)) << 4);
  const int g1 = (((4 + (lane >> 4)) ^ (fr & 7)) << 4);
  const int arow = (wr << 7) + fr;
  const int brow = (wc << 6) + fr;

  // current tile
  int v = blockIdx.x;
  if (v >= NTILES) return;
  int sw = (v & 7) * (NTILES >> 3) + (v >> 3);
  int m0 = (sw / NT) << 8, n0 = (sw - (sw / NT) * NT) << 8;
  const char* pA = (const char*)A + (size_t)(m0 + srow) * K2 + sgs;
  const char* pB = (const char*)BT + (size_t)(n0 + srow) * K2 + sgs;
  // next tile (static stride 256)
  int vn = v + 256;
  bool more = vn < NTILES;
  int m0n = m0, n0n = n0;
  const char* pAn = pA; const char* pBn = pB;
  if (more) {
    int sw2 = (vn & 7) * (NTILES >> 3) + (vn >> 3);
    m0n = (sw2 / NT) << 8; n0n = (sw2 - (sw2 / NT) * NT) << 8;
    pAn = (const char*)A + (size_t)(m0n + srow) * K2 + sgs;
    pBn = (const char*)BT + (size_t)(n0n + srow) * K2 + sgs;
  }

  f32x4 acc[8][4];
  #pragma unroll
  for (int i = 0; i < 8; ++i)
    #pragma unroll
    for (int j = 0; j < 4; ++j) acc[i][j] = (f32x4){0.f, 0.f, 0.f, 0.f};

  bf16x8 af[4][2];
  bf16x8 bbv[2][2][2];
  const int KT = K >> 6;
  const int NI = KT >> 1;

#define BARR __builtin_amdgcn_s_barrier()
#define LGKM0 asm volatile("s_waitcnt lgkmcnt(0)" ::: "memory")
#define VM6 asm volatile("s_waitcnt vmcnt(6)" ::: "memory")
#define VM0 asm volatile("s_waitcnt vmcnt(0)" ::: "memory")

#define LDA(CB, mh)                                                          \
  {                                                                          \
    const char* ba = ((const char*)&sA[0][0]) + (CB)*32768;                  \
    _Pragma("unroll") for (int fm = 0; fm < 4; ++fm) {                       \
      const int r = arow + (mh)*64 + fm * 16;                                \
      af[fm][0] = *(const bf16x8*)(ba + r * 128 + g0);                       \
      af[fm][1] = *(const bf16x8*)(ba + r * 128 + g1);                       \
    }                                                                        \
  }
#define LDB(CB, nh)                                                          \
  {                                                                          \
    const char* ba = ((const char*)&sB[0][0]) + (CB)*32768;                  \
    _Pragma("unroll") for (int fn = 0; fn < 2; ++fn) {                       \
      const int r = brow + (nh)*32 + fn * 16;                                \
      bbv[nh][fn][0] = *(const bf16x8*)(ba + r * 128 + g0);                  \
      bbv[nh][fn][1] = *(const bf16x8*)(ba + r * 128 + g1);                  \
    }                                                                        \
  }
#define STGA_(P, CB, tt, j)                                                  \
  gld16((P) + (size_t)((j)*64) * K2 + ((size_t)(tt) << 7),                   \
        sdA + (CB)*32768 + (j)*8192);
#define STGB_(P, CB, tt, j)                                                  \
  gld16((P) + (size_t)((j)*64) * K2 + ((size_t)(tt) << 7),                   \
        sdB + (CB)*32768 + (j)*8192);
#define MMAQ(mh, nh)                                                         \
  _Pragma("unroll") for (int fm = 0; fm < 4; ++fm)                           \
      _Pragma("unroll") for (int fn = 0; fn < 2; ++fn) {                     \
    f32x4* ac = &acc[(mh)*4 + fm][(nh)*2 + fn];                              \
    *ac = __builtin_amdgcn_mfma_f32_16x16x32_bf16(af[fm][0], bbv[nh][fn][0], \
                                                  *ac, 0, 0, 0);             \
    *ac = __builtin_amdgcn_mfma_f32_16x16x32_bf16(af[fm][1], bbv[nh][fn][1], \
                                                  *ac, 0, 0, 0);             \
  }
#define OPEN  BARR; LGKM0; __builtin_amdgcn_s_setprio(1)
#define CLOSE __builtin_amdgcn_s_setprio(0)

  // prologue: first tile's k-tile 0 (8 chunks) + k-tile 1 (6 chunks; A1,A3 wrap to P0)
  #pragma unroll
  for (int j = 0; j < 4; ++j) { STGA_(pA, 0, 0, j); STGB_(pB, 0, 0, j); }
  STGA_(pA, 1, 1, 0); STGA_(pA, 1, 1, 2);
  STGB_(pB, 1, 1, 0); STGB_(pB, 1, 1, 1); STGB_(pB, 1, 1, 2); STGB_(pB, 1, 1, 3);
  VM6;
  BARR;

  for (;;) {
    for (int i = 0; i < NI; ++i) {
      const bool lastit = (i == NI - 1);
      const int s1 = 2 * i + 1;
      const bool gl = (!lastit) || more;
      const char* qA = lastit ? pAn : pA;
      const char* qB = lastit ? pBn : pB;
      const int t2 = lastit ? 0 : 2 * i + 2;
      const int t3 = lastit ? 1 : 2 * i + 3;
      // ---- K-tile 2i (buf0) ----
      LDB(0, 0) LDA(0, 0)
      STGA_(pA, 1, s1, 1); STGA_(pA, 1, s1, 3);
      OPEN; MMAQ(0, 0); CLOSE; BARR;
      LDB(0, 1)
      if (gl) { STGA_(qA, 0, t2, 0); STGA_(qA, 0, t2, 2); }
      OPEN; MMAQ(0, 1); CLOSE; BARR;
      LDA(0, 1)
      if (gl) { STGB_(qB, 0, t2, 0); STGB_(qB, 0, t2, 1); }
      OPEN; MMAQ(1, 1); CLOSE; BARR;
      if (gl) { STGB_(qB, 0, t2, 2); STGB_(qB, 0, t2, 3); }
      OPEN; MMAQ(1, 0); CLOSE;
      if (gl) { VM6; } else { VM0; }
      BARR;
      // ---- K-tile 2i+1 (buf1) ----
      LDB(1, 0) LDA(1, 0)
      if (gl) { STGA_(qA, 0, t2, 1); STGA_(qA, 0, t2, 3); }
      OPEN; MMAQ(0, 0); CLOSE; BARR;
      LDB(1, 1)
      if (gl) { STGA_(qA, 1, t3, 0); STGA_(qA, 1, t3, 2); }
      OPEN; MMAQ(0, 1); CLOSE; BARR;
      LDA(1, 1)
      if (gl) { STGB_(qB, 1, t3, 0); STGB_(qB, 1, t3, 1); }
      OPEN; MMAQ(1, 1); CLOSE; BARR;
      if (gl) { STGB_(qB, 1, t3, 2); STGB_(qB, 1, t3, 3); }
      OPEN; MMAQ(1, 0); CLOSE;
      if (gl) { VM6; }
      BARR;
    }

    // ---- epilogue for finished tile (m0, n0); pure stores, pipeline stays warm ----
    #pragma unroll
    for (int ai = 0; ai < 8; ++ai) {
      #pragma unroll
      for (int bj = 0; bj < 4; ++bj) {
        const int col = n0 + (wc << 6) + bj * 16 + fr;
        const float bc = bias[col];
        #pragma unroll
        for (int i = 0; i < 4; ++i) {
          const int row = m0 + (wr << 7) + ai * 16 + q4 + i;
          float vvv = acc[ai][bj][i] + bc;
          if (EPI == 0) {
            outB[(size_t)row * N + col] = f2bf(vvv);
          } else if (EPI == 1) {
            int b = row >> 7, wid = (row >> 4) & 7, tok = row & 15;
            int oh = (((wid >> 2) << 2) + (tok >> 2) + 2) & 7;
            int ow = (((wid & 3) << 2) + (tok & 3) + 2) & 15;
            size_t di = ((size_t)(b << 7) + oh * 16 + ow) * 768 + col;
            outB[di] = f2bf(vvv + resid[di]);
          } else if (EPI == 2) {
            float g = 0.5f * vvv * (1.0f + erff(vvv * 0.70710678118f));
            outB[(size_t)row * N + col] = f2bf(g);
          } else {
            size_t di = (size_t)row * N + col;
            outF[di] = vvv + bf2f(residB[di]);
          }
          acc[ai][bj][i] = 0.f;
        }
      }
    }

    v = vn;
    if (v >= NTILES) break;
    pA = pAn; pB = pBn; m0 = m0n; n0 = n0n;
    vn += 256;
    more = (vn < NTILES);
    if (more) {
      int sw2 = (vn & 7) * (NTILES >> 3) + (vn >> 3);
      m0n = (sw2 / NT) << 8; n0n = (sw2 - (sw2 / NT) * NT) << 8;
      pAn = (const char*)A + (size_t)(m0n + srow) * K2 + sgs;
      pBn = (const char*)BT + (size_t)(n0n + srow) * K2 + sgs;
    }
  }
#undef BARR
#undef LGKM0
#undef VM6
#undef VM0
#undef LDA
#undef LDB
#undef STGA_
#undef STGB_
#undef MMAQ
#undef OPEN
#undef CLOSE
}

// ---------- window attention: one wave per (window, head), coalesced O store ----------
__global__ __launch_bounds__(64) void attn_win(const unsigned short* __restrict__ qkv,
                                               const float* __restrict__ rel_table,
                                               unsigned short* __restrict__ o) {
  __shared__ __align__(16) unsigned short vt_s[64 * 32];
  __shared__ __align__(16) unsigned short p_s[16 * 32];
  __shared__ __align__(16) unsigned short o_s[16 * 72];
  const int nwg = gridDim.x;
  const int orig = blockIdx.x;
  const int bid = (orig & 7) * (nwg >> 3) + (orig >> 3);
  const int win = bid / 12;
  const int head = bid - win * 12;
  const int wid = win & 7;
  const int lane = threadIdx.x;
  const unsigned short* qb = qkv + (size_t)win * 16 * 2304 + head * 64;
  const int t = lane >> 2, d0 = (lane & 3) << 4;
  unsigned short vv[16];
  *(uint4v*)&vv[0] = *(const uint4v*)(qb + 1536 + (size_t)t * 2304 + d0);
  *(uint4v*)&vv[8] = *(const uint4v*)(qb + 1544 + (size_t)t * 2304 + d0);
  #pragma unroll
  for (int e = 0; e < 16; ++e) vt_s[(d0 + e) * 32 + t] = vv[e];
  #pragma unroll
  for (int e = 0; e < 16; ++e) vt_s[lane * 32 + 16 + e] = 0;
  if (lane < 16) {
    #pragma unroll
    for (int e = 0; e < 16; ++e) p_s[lane * 32 + 16 + e] = 0;
  }
  __syncthreads();

  const int fr = lane & 15, g8 = (lane >> 4) << 3;
  const unsigned short* qrow = qb + (size_t)fr * 2304;
  bf16x8 qa0 = *(const bf16x8*)(qrow + g8);
  bf16x8 qa1 = *(const bf16x8*)(qrow + 32 + g8);
  bf16x8 ka0 = *(const bf16x8*)(qrow + 768 + g8);
  bf16x8 ka1 = *(const bf16x8*)(qrow + 800 + g8);
  f32x4 s = (f32x4){0.f, 0.f, 0.f, 0.f};
  s = __builtin_amdgcn_mfma_f32_16x16x32_bf16(qa0, ka0, s, 0, 0, 0);
  s = __builtin_amdgcn_mfma_f32_16x16x32_bf16(qa1, ka1, s, 0, 0, 0);

  const int wh = wid >> 2, wwc = wid & 3;
  const int rj = fr >> 2, cj = fr & 3;
  const int rowm = wh * 4 + rj, colm = wwc * 4 + cj;
  const int rgm = (rowm < 4 ? 0 : (rowm < 6 ? 1 : 2)) * 3 +
                  (colm < 12 ? 0 : (colm < 14 ? 1 : 2));
  float p[4];
  #pragma unroll
  for (int i = 0; i < 4; ++i) {
    int n = ((lane >> 4) << 2) + i;
    int ri = n >> 2, ci = n & 3;
    int rown = wh * 4 + ri, coln = wwc * 4 + ci;
    int rgn = (rown < 4 ? 0 : (rown < 6 ? 1 : 2)) * 3 +
              (coln < 12 ? 0 : (coln < 14 ? 1 : 2));
    float bias = rel_table[(size_t)((ri - rj + 3) * 7 + (ci - cj + 3)) * 12 + head];
    p[i] = s[i] * 0.125f + bias + (rgn != rgm ? -100.0f : 0.0f);
  }
  float mx[4] = {p[0], p[1], p[2], p[3]};
  #pragma unroll
  for (int off = 8; off > 0; off >>= 1)
    #pragma unroll
    for (int i = 0; i < 4; ++i) mx[i] = fmaxf(mx[i], __shfl_xor(mx[i], off, 64));
  float sm[4];
  #pragma unroll
  for (int i = 0; i < 4; ++i) { p[i] = __expf(p[i] - mx[i]); sm[i] = p[i]; }
  #pragma unroll
  for (int off = 8; off > 0; off >>= 1)
    #pragma unroll
    for (int i = 0; i < 4; ++i) sm[i] += __shfl_xor(sm[i], off, 64);
  #pragma unroll
  for (int i = 0; i < 4; ++i)
    p_s[(((lane >> 4) << 2) + i) * 32 + fr] = f2bf(p[i] / sm[i]);
  __syncthreads();

  bf16x8 pa = *(const bf16x8*)&p_s[fr * 32 + g8];
  const f32x4 oz = (f32x4){0.f, 0.f, 0.f, 0.f};
  #pragma unroll
  for (int c = 0; c < 4; ++c) {
    bf16x8 vb = *(const bf16x8*)&vt_s[(c * 16 + fr) * 32 + g8];
    f32x4 oa = __builtin_amdgcn_mfma_f32_16x16x32_bf16(pa, vb, oz, 0, 0, 0);
    #pragma unroll
    for (int i = 0; i < 4; ++i) {
      int n = ((lane >> 4) << 2) + i;
      o_s[n * 72 + c * 16 + fr] = f2bf(oa[i]);
    }
  }
  __syncthreads();
  const int orow = lane >> 2, oq = lane & 3;
  const unsigned short* srcp = &o_s[orow * 72 + oq * 16];
  unsigned short* dstp = o + ((size_t)win * 16 + orow) * 768 + head * 64 + oq * 16;
  *(uint4v*)dstp = *(const uint4v*)srcp;
  *(uint4v*)(dstp + 8) = *(const uint4v*)(srcp + 8);
}

extern "C" void kernel_launch(void* const* d_in, const int* in_sizes, int n_in,
                              void* d_out, int out_size, void* d_ws, size_t ws_size,
                              hipStream_t stream) {
  const float* x      = (const float*)d_in[0];
  const float* ln1_g  = (const float*)d_in[1];
  const float* ln1_b  = (const float*)d_in[2];
  const float* qkv_w  = (const float*)d_in[3];
  const float* qkv_b  = (const float*)d_in[4];
  const float* proj_w = (const float*)d_in[5];
  const float* proj_b = (const float*)d_in[6];
  const float* rel_t  = (const float*)d_in[7];
  const float* ln2_g  = (const float*)d_in[8];
  const float* ln2_b  = (const float*)d_in[9];
  const float* fc1_w  = (const float*)d_in[10];
  const float* fc1_b  = (const float*)d_in[11];
  const float* fc2_w  = (const float*)d_in[12];
  const float* fc2_b  = (const float*)d_in[13];
  float* out = (float*)d_out;

  char* ws = (char*)d_ws;
  unsigned short* wsA = (unsigned short*)(ws);
  unsigned short* qkvb = (unsigned short*)(ws + 50331648);
  unsigned short* xr16 = (unsigned short*)(ws + 50331648);
  unsigned short* h1 = (unsigned short*)(ws + 201326592);
  unsigned short* qkv_wT = (unsigned short*)(ws + 268435456);  // [2304][768]
  unsigned short* proj_wT = (unsigned short*)(ws + 271974400); // [768][768]
  unsigned short* fc1_wT = (unsigned short*)(ws + 273154048);  // [1024][768]
  unsigned short* fc2_wT = (unsigned short*)(ws + 274726912);  // [768][1024]

  fused_pre<<<36608, 256, 0, stream>>>(qkv_w, qkv_wT, proj_w, proj_wT,
                                       fc1_w, fc1_wT, fc2_w, fc2_wT,
                                       x, ln1_g, ln1_b, wsA);                    // weights + hw

  gemm256<0><<<256, 512, 0, stream>>>(wsA, qkv_wT, qkv_b, nullptr, qkvb,
                                      nullptr, nullptr,
                                      32768, 2304, 768, 9, 1152);                // qkv
  attn_win<<<24576, 64, 0, stream>>>(qkvb, rel_t, wsA);                          // o
  gemm256<1><<<256, 512, 0, stream>>>(wsA, proj_wT, proj_b, nullptr, xr16,
                                      x, nullptr,
                                      32768, 768, 768, 3, 384);                  // xr16 = bf16(x + proj(o))
  ln2_kernel<<<32768, 256, 0, stream>>>(xr16, ln2_g, ln2_b, wsA);                // y
  gemm256<2><<<256, 512, 0, stream>>>(wsA, fc1_wT, fc1_b, nullptr, h1,
                                      nullptr, nullptr,
                                      32768, 1024, 768, 4, 512);                 // h1 = gelu(...)
  gemm256<3><<<256, 512, 0, stream>>>(h1, fc2_wT, fc2_b, out, nullptr,
                                      nullptr, xr16,
                                      32768, 768, 1024, 3, 384);                 // out = xr + fc2(h1)
}